// Round 8
// baseline (397.887 us; speedup 1.0000x reference)
//
#include <hip/hip_runtime.h>
#include <cstdint>

#define NEG_SLOPE 0.2f

__device__ __forceinline__ float leaky(float v) { return v > 0.f ? v : NEG_SLOPE * v; }
__device__ __forceinline__ float elu(float v) { return v > 0.f ? v : __expf(v) - 1.f; }

typedef _Float16 half2v __attribute__((ext_vector_type(2)));
union H8 { float4 f4; half2v h[4]; };   // 16 B = 8 halves
union H4 { float2 f2; half2v h[2]; };   // 8 B = 4 halves

// ---------------- single-dispatch CSR build ----------------
// 256 blocks x 512 threads: <=32 waves/CU even in worst-case packing -> always
// co-resident, so a software grid barrier is safe. Monotonic arrival counter
// (no reset races); agent-scope atomic loads where this block's L1 may be stale.

__device__ __forceinline__ void gridbar(unsigned* bar, unsigned target) {
    __syncthreads();
    if (threadIdx.x == 0) {
        __threadfence();
        __hip_atomic_fetch_add(bar, 1u, __ATOMIC_ACQ_REL, __HIP_MEMORY_SCOPE_AGENT);
        while (__hip_atomic_load(bar, __ATOMIC_ACQUIRE, __HIP_MEMORY_SCOPE_AGENT) < target)
            __builtin_amdgcn_s_sleep(1);
    }
    __syncthreads();
}

__global__ __launch_bounds__(512) void csr_kernel(const int* __restrict__ src,
                                                  const int* __restrict__ dst,
                                                  int* __restrict__ cnt,
                                                  int* __restrict__ rp,
                                                  int* __restrict__ cur,
                                                  int* __restrict__ col,
                                                  int* __restrict__ bsum,
                                                  unsigned* __restrict__ bar,
                                                  int n, int E) {
    int b = blockIdx.x, t = threadIdx.x;
    int gtid = b * 512 + t;
    // phase 0: zero counts
    for (int i = gtid; i < n; i += 131072) cnt[i] = 0;
    gridbar(bar, 256);
    // phase 1: count in-degrees
    for (int i = gtid; i < E; i += 131072) atomicAdd(&cnt[dst[i]], 1);
    gridbar(bar, 512);
    // phase 2: block-local inclusive scan of this block's 512-chunk
    __shared__ int sm[512];
    __shared__ int bs[256];
    int idx = b * 512 + t;
    int v = 0;
    if (idx < n) v = __hip_atomic_load(&cnt[idx], __ATOMIC_RELAXED, __HIP_MEMORY_SCOPE_AGENT);
    sm[t] = v;
    __syncthreads();
    for (int o = 1; o < 512; o <<= 1) {
        int u = (t >= o) ? sm[t - o] : 0;
        __syncthreads();
        sm[t] += u;
        __syncthreads();
    }
    if (t == 511) bsum[b] = sm[511];
    gridbar(bar, 768);
    // phase 3: every block redundantly scans the 256 block sums, writes rp/cur
    int bv = 0;
    if (t < 256) bv = __hip_atomic_load(&bsum[t], __ATOMIC_RELAXED, __HIP_MEMORY_SCOPE_AGENT);
    if (t < 256) bs[t] = bv;
    __syncthreads();
    for (int o = 1; o < 256; o <<= 1) {
        int u = (t >= o && t < 256) ? bs[t - o] : 0;
        __syncthreads();
        if (t < 256) bs[t] += u;
        __syncthreads();
    }
    int blockPrefix = (b == 0) ? 0 : bs[b - 1];
    int excl = blockPrefix + sm[t] - v;
    if (idx <= n) rp[idx] = excl;
    if (idx < n) cur[idx] = excl;
    gridbar(bar, 1024);
    // phase 4: scatter src into dst-sorted col
    for (int i = gtid; i < E; i += 131072) {
        int pos = atomicAdd(&cur[dst[i]], 1);
        col[pos] = src[i];
    }
}

// ---------------- GEMM1: h1 = x @ W1 (fp16 out) + fused alpha dots (fp32) ----------

__global__ __launch_bounds__(128) void gemm1_kernel(const float* __restrict__ x,
                                                    const float* __restrict__ W,
                                                    const float* __restrict__ a_src,
                                                    const float* __restrict__ a_dst,
                                                    _Float16* __restrict__ h1h,
                                                    float* __restrict__ as1,
                                                    float* __restrict__ ad1, int n) {
    __shared__ float xl[64][129];
    __shared__ float Wl[64 * 128];
    int tid = threadIdx.x;
    int row0 = blockIdx.x * 64;
    for (int i = 0; i < 16; ++i) {
        int idx = tid + i * 128;            // float4 index over 64x32
        int r = idx >> 5, c4 = idx & 31;
        float4 v = make_float4(0.f, 0.f, 0.f, 0.f);
        if (row0 + r < n) v = *(const float4*)(x + (size_t)(row0 + r) * 128 + c4 * 4);
        xl[r][c4 * 4 + 0] = v.x; xl[r][c4 * 4 + 1] = v.y;
        xl[r][c4 * 4 + 2] = v.z; xl[r][c4 * 4 + 3] = v.w;
    }
    int r0 = (tid >> 4) * 8, c0 = (tid & 15) * 4;
    float4 acc[8][2];
#pragma unroll
    for (int r = 0; r < 8; ++r) {
        acc[r][0] = make_float4(0.f, 0.f, 0.f, 0.f);
        acc[r][1] = make_float4(0.f, 0.f, 0.f, 0.f);
    }
    const float4* W4 = (const float4*)W;
    float4* Wl4 = (float4*)Wl;
    for (int kb = 0; kb < 2; ++kb) {
        __syncthreads();
#pragma unroll
        for (int i = 0; i < 16; ++i) Wl4[tid + i * 128] = W4[kb * 2048 + tid + i * 128];
        __syncthreads();
        for (int k = 0; k < 64; ++k) {
            float4 w0 = *(float4*)&Wl[k * 128 + c0];
            float4 w1 = *(float4*)&Wl[k * 128 + c0 + 64];
            int kk = kb * 64 + k;
#pragma unroll
            for (int r = 0; r < 8; ++r) {
                float xv = xl[r0 + r][kk];
                acc[r][0].x += xv * w0.x; acc[r][0].y += xv * w0.y;
                acc[r][0].z += xv * w0.z; acc[r][0].w += xv * w0.w;
                acc[r][1].x += xv * w1.x; acc[r][1].y += xv * w1.y;
                acc[r][1].z += xv * w1.z; acc[r][1].w += xv * w1.w;
            }
        }
    }
    int h0 = c0 >> 5;           // head for cols c0..c0+3 (0/1); c0+64 -> h0+2
    int cc = c0 & 31;
    float as0[4], as1v[4], ad0[4], ad1v[4];
#pragma unroll
    for (int j = 0; j < 4; ++j) {
        as0[j] = a_src[h0 * 32 + cc + j];
        as1v[j] = a_src[(h0 + 2) * 32 + cc + j];
        ad0[j] = a_dst[h0 * 32 + cc + j];
        ad1v[j] = a_dst[(h0 + 2) * 32 + cc + j];
    }
#pragma unroll
    for (int r = 0; r < 8; ++r) {
        int row = row0 + r0 + r;
        float4 a0 = acc[r][0], a1 = acc[r][1];
        float ps0 = a0.x * as0[0] + a0.y * as0[1] + a0.z * as0[2] + a0.w * as0[3];
        float ps1 = a1.x * as1v[0] + a1.y * as1v[1] + a1.z * as1v[2] + a1.w * as1v[3];
        float pd0 = a0.x * ad0[0] + a0.y * ad0[1] + a0.z * ad0[2] + a0.w * ad0[3];
        float pd1 = a1.x * ad1v[0] + a1.y * ad1v[1] + a1.z * ad1v[2] + a1.w * ad1v[3];
#pragma unroll
        for (int o = 1; o < 8; o <<= 1) {
            ps0 += __shfl_xor(ps0, o); ps1 += __shfl_xor(ps1, o);
            pd0 += __shfl_xor(pd0, o); pd1 += __shfl_xor(pd1, o);
        }
        if (row < n) {
            H4 u0, u1;
            u0.h[0] = half2v{(_Float16)a0.x, (_Float16)a0.y};
            u0.h[1] = half2v{(_Float16)a0.z, (_Float16)a0.w};
            u1.h[0] = half2v{(_Float16)a1.x, (_Float16)a1.y};
            u1.h[1] = half2v{(_Float16)a1.z, (_Float16)a1.w};
            *(float2*)&h1h[(size_t)row * 128 + c0] = u0.f2;
            *(float2*)&h1h[(size_t)row * 128 + c0 + 64] = u1.f2;
            if ((tid & 7) == 0) {
                as1[row * 4 + h0] = ps0; as1[row * 4 + h0 + 2] = ps1;
                ad1[row * 4 + h0] = pd0; ad1[row * 4 + h0 + 2] = pd1;
            }
        }
    }
}

// ---------------- GEMM2: h2 = hp @ W2 (fp16 in/out) + fused alpha dots ----------------

__global__ __launch_bounds__(256) void gemm2_kernel(const _Float16* __restrict__ hph,
                                                    const float* __restrict__ W2,
                                                    const float* __restrict__ a_src,
                                                    const float* __restrict__ a_dst,
                                                    _Float16* __restrict__ h2h,
                                                    float* __restrict__ as2,
                                                    float* __restrict__ ad2, int n) {
    __shared__ float Wl[128 * 32];
    __shared__ float xl[32][129];
    int tid = threadIdx.x;
    const float4* W4 = (const float4*)W2;
    float4* Wl4 = (float4*)Wl;
#pragma unroll
    for (int i = 0; i < 4; ++i) Wl4[tid + i * 256] = W4[tid + i * 256];
    int row0 = blockIdx.x * 32;
    for (int f = tid; f < 32 * 128; f += 256) {
        int r = f >> 7, k = f & 127;
        int row = row0 + r;
        xl[r][k] = (row < n) ? (float)hph[(size_t)row * 128 + k] : 0.f;
    }
    __syncthreads();
    int cg = tid & 7, r = tid >> 3;
    int c0 = cg * 4;
    float a0 = 0, a1 = 0, a2 = 0, a3 = 0;
    for (int k = 0; k < 128; ++k) {
        float4 w = *(const float4*)&Wl[k * 32 + c0];
        float xv = xl[r][k];
        a0 += xv * w.x; a1 += xv * w.y; a2 += xv * w.z; a3 += xv * w.w;
    }
    float ps = a0 * a_src[c0] + a1 * a_src[c0 + 1] + a2 * a_src[c0 + 2] + a3 * a_src[c0 + 3];
    float pd = a0 * a_dst[c0] + a1 * a_dst[c0 + 1] + a2 * a_dst[c0 + 2] + a3 * a_dst[c0 + 3];
#pragma unroll
    for (int o = 1; o < 8; o <<= 1) { ps += __shfl_xor(ps, o); pd += __shfl_xor(pd, o); }
    int row = row0 + r;
    if (row < n) {
        H4 u;
        u.h[0] = half2v{(_Float16)a0, (_Float16)a1};
        u.h[1] = half2v{(_Float16)a2, (_Float16)a3};
        *(float2*)&h2h[(size_t)row * 32 + c0] = u.f2;
        if (cg == 0) { as2[row] = ps; ad2[row] = pd; }
    }
}

// ---------------- layer-1 softmax + aggregate: wave/node, fp16 gather ----------------
// Lane g=lane&7 owns ch [g*8,g*8+8) (head g<4?0:1) and [64+g*8,..) (head g<4?2:3);
// sub=lane>>3 is the edge subset. Gather loads are 16 B x 8 consecutive lanes.
// FMA pattern (float)h * p + acc -> v_fma_mix_f32.

__global__ __launch_bounds__(256) void agg1_kernel(const _Float16* __restrict__ h1h,
                                                   const float4* __restrict__ as1,
                                                   const float4* __restrict__ ad1,
                                                   const int* __restrict__ rp,
                                                   const int* __restrict__ col,
                                                   const float* __restrict__ b1,
                                                   _Float16* __restrict__ hph, int n) {
    __shared__ float4 s_p[4][64];
    int wave = threadIdx.x >> 6, lane = threadIdx.x & 63;
    int nid = blockIdx.x * 4 + wave;
    if (nid >= n) return;
    int start = rp[nid], end = rp[nid + 1];
    float4 adn = ad1[nid], asn = as1[nid];
    float4 psf;
    psf.x = __expf(leaky(asn.x + adn.x));
    psf.y = __expf(leaky(asn.y + adn.y));
    psf.z = __expf(leaky(asn.z + adn.z));
    psf.w = __expf(leaky(asn.w + adn.w));
    float4 dsum = make_float4(0.f, 0.f, 0.f, 0.f);
    int g = lane & 7, sub = lane >> 3;
    float4 aL0 = make_float4(0.f, 0.f, 0.f, 0.f);
    float4 aL1 = aL0, aH0 = aL0, aH1 = aL0;

    for (int base = start; base < end; base += 64) {
        int i = base + lane;
        int sidx = 0;
        float4 p = make_float4(0.f, 0.f, 0.f, 0.f);
        if (i < end) {
            sidx = col[i];
            float4 a = as1[sidx];
            p.x = __expf(leaky(a.x + adn.x));
            p.y = __expf(leaky(a.y + adn.y));
            p.z = __expf(leaky(a.z + adn.z));
            p.w = __expf(leaky(a.w + adn.w));
            dsum.x += p.x; dsum.y += p.y; dsum.z += p.z; dsum.w += p.w;
        }
        s_p[wave][lane] = p;         // intra-wave LDS, program order per wave
        int len = min(64, end - base);
        int steps = (len + 7) >> 3;  // wave-uniform
        for (int s = 0; s < steps; ++s) {
            int j = s * 8 + sub;
            int js = (j < len) ? j : 0;
            int rj = __shfl(sidx, js);           // all 64 lanes active
            if (j < len) {
                float4 pv = s_p[wave][js];
                float wl = (g < 4) ? pv.x : pv.y;
                float wh = (g < 4) ? pv.z : pv.w;
                const H8* row = (const H8*)(h1h + (size_t)rj * 128);
                H8 u0 = row[g], u1 = row[8 + g];
                aL0.x += (float)u0.h[0].x * wl; aL0.y += (float)u0.h[0].y * wl;
                aL0.z += (float)u0.h[1].x * wl; aL0.w += (float)u0.h[1].y * wl;
                aL1.x += (float)u0.h[2].x * wl; aL1.y += (float)u0.h[2].y * wl;
                aL1.z += (float)u0.h[3].x * wl; aL1.w += (float)u0.h[3].y * wl;
                aH0.x += (float)u1.h[0].x * wh; aH0.y += (float)u1.h[0].y * wh;
                aH0.z += (float)u1.h[1].x * wh; aH0.w += (float)u1.h[1].y * wh;
                aH1.x += (float)u1.h[2].x * wh; aH1.y += (float)u1.h[2].y * wh;
                aH1.z += (float)u1.h[3].x * wh; aH1.w += (float)u1.h[3].y * wh;
            }
        }
    }
    // self loop (one edge-subset adds it)
    if (sub == 0) {
        float wl = (g < 4) ? psf.x : psf.y;
        float wh = (g < 4) ? psf.z : psf.w;
        const H8* row = (const H8*)(h1h + (size_t)nid * 128);
        H8 u0 = row[g], u1 = row[8 + g];
        aL0.x += (float)u0.h[0].x * wl; aL0.y += (float)u0.h[0].y * wl;
        aL0.z += (float)u0.h[1].x * wl; aL0.w += (float)u0.h[1].y * wl;
        aL1.x += (float)u0.h[2].x * wl; aL1.y += (float)u0.h[2].y * wl;
        aL1.z += (float)u0.h[3].x * wl; aL1.w += (float)u0.h[3].y * wl;
        aH0.x += (float)u1.h[0].x * wh; aH0.y += (float)u1.h[0].y * wh;
        aH0.z += (float)u1.h[1].x * wh; aH0.w += (float)u1.h[1].y * wh;
        aH1.x += (float)u1.h[2].x * wh; aH1.y += (float)u1.h[2].y * wh;
        aH1.z += (float)u1.h[3].x * wh; aH1.w += (float)u1.h[3].y * wh;
    }
    if (lane == 0) {
        dsum.x += psf.x; dsum.y += psf.y; dsum.z += psf.z; dsum.w += psf.w;
    }
#pragma unroll
    for (int o = 1; o < 64; o <<= 1) {
        dsum.x += __shfl_xor(dsum.x, o); dsum.y += __shfl_xor(dsum.y, o);
        dsum.z += __shfl_xor(dsum.z, o); dsum.w += __shfl_xor(dsum.w, o);
    }
#pragma unroll
    for (int o = 8; o < 64; o <<= 1) {    // reduce over edge subsets (same g)
        aL0.x += __shfl_xor(aL0.x, o); aL0.y += __shfl_xor(aL0.y, o);
        aL0.z += __shfl_xor(aL0.z, o); aL0.w += __shfl_xor(aL0.w, o);
        aL1.x += __shfl_xor(aL1.x, o); aL1.y += __shfl_xor(aL1.y, o);
        aL1.z += __shfl_xor(aL1.z, o); aL1.w += __shfl_xor(aL1.w, o);
        aH0.x += __shfl_xor(aH0.x, o); aH0.y += __shfl_xor(aH0.y, o);
        aH0.z += __shfl_xor(aH0.z, o); aH0.w += __shfl_xor(aH0.w, o);
        aH1.x += __shfl_xor(aH1.x, o); aH1.y += __shfl_xor(aH1.y, o);
        aH1.z += __shfl_xor(aH1.z, o); aH1.w += __shfl_xor(aH1.w, o);
    }
    if (sub == 0) {
        float i0 = __builtin_amdgcn_rcpf(dsum.x);
        float i1 = __builtin_amdgcn_rcpf(dsum.y);
        float i2 = __builtin_amdgcn_rcpf(dsum.z);
        float i3 = __builtin_amdgcn_rcpf(dsum.w);
        float il = (g < 4) ? i0 : i1;
        float ih = (g < 4) ? i2 : i3;
        const float4* b4 = (const float4*)b1;
        float4 bL0 = b4[g * 2], bL1 = b4[g * 2 + 1];
        float4 bH0 = b4[16 + g * 2], bH1 = b4[16 + g * 2 + 1];
        float4 r0 = make_float4(elu(aL0.x * il + bL0.x), elu(aL0.y * il + bL0.y),
                                elu(aL0.z * il + bL0.z), elu(aL0.w * il + bL0.w));
        float4 r1 = make_float4(elu(aL1.x * il + bL1.x), elu(aL1.y * il + bL1.y),
                                elu(aL1.z * il + bL1.z), elu(aL1.w * il + bL1.w));
        float4 r2 = make_float4(elu(aH0.x * ih + bH0.x), elu(aH0.y * ih + bH0.y),
                                elu(aH0.z * ih + bH0.z), elu(aH0.w * ih + bH0.w));
        float4 r3 = make_float4(elu(aH1.x * ih + bH1.x), elu(aH1.y * ih + bH1.y),
                                elu(aH1.z * ih + bH1.z), elu(aH1.w * ih + bH1.w));
        H8 oL, oH;
        oL.h[0] = half2v{(_Float16)r0.x, (_Float16)r0.y};
        oL.h[1] = half2v{(_Float16)r0.z, (_Float16)r0.w};
        oL.h[2] = half2v{(_Float16)r1.x, (_Float16)r1.y};
        oL.h[3] = half2v{(_Float16)r1.z, (_Float16)r1.w};
        oH.h[0] = half2v{(_Float16)r2.x, (_Float16)r2.y};
        oH.h[1] = half2v{(_Float16)r2.z, (_Float16)r2.w};
        oH.h[2] = half2v{(_Float16)r3.x, (_Float16)r3.y};
        oH.h[3] = half2v{(_Float16)r3.z, (_Float16)r3.w};
        *(float4*)&hph[(size_t)nid * 128 + g * 8] = oL.f4;
        *(float4*)&hph[(size_t)nid * 128 + 64 + g * 8] = oH.f4;
    }
}

// ---------------- layer-2 softmax + aggregate: wave/node, fp16 gather ----------------

__global__ __launch_bounds__(256) void agg2_kernel(const _Float16* __restrict__ h2h,
                                                   const float* __restrict__ as2,
                                                   const float* __restrict__ ad2,
                                                   const int* __restrict__ rp,
                                                   const int* __restrict__ col,
                                                   const float* __restrict__ b2,
                                                   float* __restrict__ out, int n) {
    int wave = threadIdx.x >> 6, lane = threadIdx.x & 63;
    int nid = blockIdx.x * 4 + wave;
    if (nid >= n) return;
    int start = rp[nid], end = rp[nid + 1];
    float adn = ad2[nid];
    float psf = __expf(leaky(as2[nid] + adn));
    float dsum = 0.f;
    int g = lane & 7, sub = lane >> 3;
    float4 acc = make_float4(0.f, 0.f, 0.f, 0.f);
    for (int base = start; base < end; base += 64) {
        int i = base + lane;
        int sidx = 0;
        float p = 0.f;
        if (i < end) {
            sidx = col[i];
            p = __expf(leaky(as2[sidx] + adn));
            dsum += p;
        }
        int len = min(64, end - base);
        int steps = (len + 7) >> 3;
        for (int s = 0; s < steps; ++s) {
            int j = s * 8 + sub;
            int js = (j < len) ? j : 0;
            int rj = __shfl(sidx, js);
            float pj = __shfl(p, js);
            if (j < len) {
                H4 u = ((const H4*)(h2h + (size_t)rj * 32))[g];
                acc.x += (float)u.h[0].x * pj; acc.y += (float)u.h[0].y * pj;
                acc.z += (float)u.h[1].x * pj; acc.w += (float)u.h[1].y * pj;
            }
        }
    }
    if (sub == 0) {
        H4 u = ((const H4*)(h2h + (size_t)nid * 32))[g];
        acc.x += (float)u.h[0].x * psf; acc.y += (float)u.h[0].y * psf;
        acc.z += (float)u.h[1].x * psf; acc.w += (float)u.h[1].y * psf;
    }
    if (lane == 0) dsum += psf;
#pragma unroll
    for (int o = 1; o < 64; o <<= 1) dsum += __shfl_xor(dsum, o);
#pragma unroll
    for (int o = 8; o < 64; o <<= 1) {
        acc.x += __shfl_xor(acc.x, o); acc.y += __shfl_xor(acc.y, o);
        acc.z += __shfl_xor(acc.z, o); acc.w += __shfl_xor(acc.w, o);
    }
    if (sub == 0) {
        float inv = __builtin_amdgcn_rcpf(dsum);
        float4 bb = ((const float4*)b2)[g];
        ((float4*)(out + (size_t)nid * 32))[g] =
            make_float4(acc.x * inv + bb.x, acc.y * inv + bb.y,
                        acc.z * inv + bb.z, acc.w * inv + bb.w);
    }
}

// ---------------- launch ----------------

extern "C" void kernel_launch(void* const* d_in, const int* in_sizes, int n_in,
                              void* d_out, int out_size, void* d_ws, size_t ws_size,
                              hipStream_t stream) {
    const float* x      = (const float*)d_in[0];
    const int*   ei     = (const int*)d_in[1];
    const float* W1     = (const float*)d_in[2];
    const float* a_src1 = (const float*)d_in[3];
    const float* a_dst1 = (const float*)d_in[4];
    const float* b1     = (const float*)d_in[5];
    const float* W2     = (const float*)d_in[6];
    const float* a_src2 = (const float*)d_in[7];
    const float* a_dst2 = (const float*)d_in[8];
    const float* b2     = (const float*)d_in[9];
    float* out = (float*)d_out;

    const int N = in_sizes[0] / 128;
    const int E = in_sizes[1] / 2;
    const int* src = ei;
    const int* dstp = ei + E;

    uint8_t* w = (uint8_t*)d_ws;
    auto carve = [&](size_t bytes) {
        uint8_t* p = w;
        w += (bytes + 255) & ~(size_t)255;
        return p;
    };
    _Float16* h1h = (_Float16*)carve((size_t)N * 128 * 2);
    _Float16* hph = (_Float16*)carve((size_t)N * 128 * 2);
    _Float16* h2h = (_Float16*)carve((size_t)N * 32 * 2);
    float* as1 = (float*)carve((size_t)N * 4 * 4);
    float* ad1 = (float*)carve((size_t)N * 4 * 4);
    float* as2 = (float*)carve((size_t)N * 4);
    float* ad2 = (float*)carve((size_t)N * 4);
    int* rp   = (int*)carve((size_t)(N + 1) * 4);
    int* cnt  = (int*)carve((size_t)N * 4);
    int* cur  = (int*)carve((size_t)N * 4);
    int* col  = (int*)carve((size_t)E * 4);
    int* bsum = (int*)carve(256 * 4);
    unsigned* bar = (unsigned*)carve(256);

    // CSR build: one dispatch (zero/count/scan/scatter with software grid barrier)
    hipMemsetAsync(bar, 0, 4, stream);
    csr_kernel<<<256, 512, 0, stream>>>(src, dstp, cnt, rp, cur, col, bsum, bar, N, E);

    // layer 1
    gemm1_kernel<<<(N + 63) / 64, 128, 0, stream>>>(x, W1, a_src1, a_dst1, h1h, as1, ad1, N);
    agg1_kernel<<<(N + 3) / 4, 256, 0, stream>>>(h1h, (const float4*)as1, (const float4*)ad1,
                                                 rp, col, b1, hph, N);
    // layer 2
    gemm2_kernel<<<(N + 31) / 32, 256, 0, stream>>>(hph, W2, a_src2, a_dst2, h2h, as2, ad2, N);
    agg2_kernel<<<(N + 3) / 4, 256, 0, stream>>>(h2h, as2, ad2, rp, col, b2, out, N);
}

// Round 9
// 321.231 us; speedup vs baseline: 1.2386x; 1.2386x over previous
//
#include <hip/hip_runtime.h>
#include <cstdint>

#define NEG_SLOPE 0.2f

__device__ __forceinline__ float leaky(float v) { return v > 0.f ? v : NEG_SLOPE * v; }
__device__ __forceinline__ float elu(float v) { return v > 0.f ? v : __expf(v) - 1.f; }

typedef _Float16 half2v __attribute__((ext_vector_type(2)));
union H8 { float4 f4; half2v h[4]; };   // 16 B = 8 halves
union H4 { float2 f2; half2v h[2]; };   // 8 B = 4 halves

// ---------------- CSR build (multi-dispatch; software grid barriers are ~4x
// slower than dispatch boundaries on MI355X — measured round 8) ----------------

__global__ void count_kernel(const int* __restrict__ dst, int* __restrict__ cnt, int E) {
    int i = blockIdx.x * blockDim.x + threadIdx.x;
    if (i < E) atomicAdd(&cnt[dst[i]], 1);
}

__global__ __launch_bounds__(256) void scanA_kernel(const int* __restrict__ cnt,
                                                    int* __restrict__ bsum, int n) {
    int base = blockIdx.x * 1024 + threadIdx.x * 4;
    int s = 0;
    if (base + 3 < n) {
        int4 v = *(const int4*)(cnt + base);
        s = v.x + v.y + v.z + v.w;
    } else {
        for (int j = 0; j < 4; ++j) if (base + j < n) s += cnt[base + j];
    }
#pragma unroll
    for (int o = 1; o < 64; o <<= 1) s += __shfl_xor(s, o);
    __shared__ int ws_[4];
    if ((threadIdx.x & 63) == 0) ws_[threadIdx.x >> 6] = s;
    __syncthreads();
    if (threadIdx.x == 0) bsum[blockIdx.x] = ws_[0] + ws_[1] + ws_[2] + ws_[3];
}

__global__ __launch_bounds__(1024) void scanB_kernel(int* __restrict__ bsum, int G) {
    __shared__ int sm[1024];
    int t = threadIdx.x;
    sm[t] = (t < G) ? bsum[t] : 0;
    __syncthreads();
    for (int o = 1; o < 1024; o <<= 1) {
        int u = (t >= o) ? sm[t - o] : 0;
        __syncthreads();
        sm[t] += u;
        __syncthreads();
    }
    if (t < G) bsum[t] = sm[t];
}

__global__ __launch_bounds__(256) void scanC_kernel(const int* __restrict__ cnt,
                                                    const int* __restrict__ bscan,
                                                    int* __restrict__ rp,
                                                    int* __restrict__ cur, int n) {
    int b = blockIdx.x, t = threadIdx.x;
    int base = b * 1024 + t * 4;
    int v[4]; int s = 0;
#pragma unroll
    for (int j = 0; j < 4; ++j) { int idx = base + j; v[j] = (idx < n) ? cnt[idx] : 0; s += v[j]; }
    int lane = t & 63;
    int x = s;
#pragma unroll
    for (int o = 1; o < 64; o <<= 1) { int u = __shfl_up(x, o); if (lane >= o) x += u; }
    __shared__ int wsum[4], woff[4];
    if (lane == 63) wsum[t >> 6] = x;
    __syncthreads();
    if (t == 0) { int a = 0; for (int i = 0; i < 4; ++i) { woff[i] = a; a += wsum[i]; } }
    __syncthreads();
    int off = ((b == 0) ? 0 : bscan[b - 1]) + (x - s) + woff[t >> 6];
#pragma unroll
    for (int j = 0; j < 4; ++j) {
        int idx = base + j;
        if (idx <= n) rp[idx] = off;
        if (idx < n) cur[idx] = off;
        off += v[j];
    }
}

__global__ void scatter_kernel(const int* __restrict__ src, const int* __restrict__ dst,
                               int* __restrict__ cur, int* __restrict__ col, int E) {
    int i = blockIdx.x * blockDim.x + threadIdx.x;
    if (i < E) {
        int pos = atomicAdd(&cur[dst[i]], 1);
        col[pos] = src[i];
    }
}

// ---------------- GEMM1: h1 = x @ W1 (fp16 out) + fused alpha dots (fp32) ----------

__global__ __launch_bounds__(128) void gemm1_kernel(const float* __restrict__ x,
                                                    const float* __restrict__ W,
                                                    const float* __restrict__ a_src,
                                                    const float* __restrict__ a_dst,
                                                    _Float16* __restrict__ h1h,
                                                    float* __restrict__ as1,
                                                    float* __restrict__ ad1, int n) {
    __shared__ float xl[64][129];
    __shared__ float Wl[64 * 128];
    int tid = threadIdx.x;
    int row0 = blockIdx.x * 64;
    for (int i = 0; i < 16; ++i) {
        int idx = tid + i * 128;            // float4 index over 64x32
        int r = idx >> 5, c4 = idx & 31;
        float4 v = make_float4(0.f, 0.f, 0.f, 0.f);
        if (row0 + r < n) v = *(const float4*)(x + (size_t)(row0 + r) * 128 + c4 * 4);
        xl[r][c4 * 4 + 0] = v.x; xl[r][c4 * 4 + 1] = v.y;
        xl[r][c4 * 4 + 2] = v.z; xl[r][c4 * 4 + 3] = v.w;
    }
    int r0 = (tid >> 4) * 8, c0 = (tid & 15) * 4;
    float4 acc[8][2];
#pragma unroll
    for (int r = 0; r < 8; ++r) {
        acc[r][0] = make_float4(0.f, 0.f, 0.f, 0.f);
        acc[r][1] = make_float4(0.f, 0.f, 0.f, 0.f);
    }
    const float4* W4 = (const float4*)W;
    float4* Wl4 = (float4*)Wl;
    for (int kb = 0; kb < 2; ++kb) {
        __syncthreads();
#pragma unroll
        for (int i = 0; i < 16; ++i) Wl4[tid + i * 128] = W4[kb * 2048 + tid + i * 128];
        __syncthreads();
        for (int k = 0; k < 64; ++k) {
            float4 w0 = *(float4*)&Wl[k * 128 + c0];
            float4 w1 = *(float4*)&Wl[k * 128 + c0 + 64];
            int kk = kb * 64 + k;
#pragma unroll
            for (int r = 0; r < 8; ++r) {
                float xv = xl[r0 + r][kk];
                acc[r][0].x += xv * w0.x; acc[r][0].y += xv * w0.y;
                acc[r][0].z += xv * w0.z; acc[r][0].w += xv * w0.w;
                acc[r][1].x += xv * w1.x; acc[r][1].y += xv * w1.y;
                acc[r][1].z += xv * w1.z; acc[r][1].w += xv * w1.w;
            }
        }
    }
    int h0 = c0 >> 5;           // head for cols c0..c0+3 (0/1); c0+64 -> h0+2
    int cc = c0 & 31;
    float as0[4], as1v[4], ad0[4], ad1v[4];
#pragma unroll
    for (int j = 0; j < 4; ++j) {
        as0[j] = a_src[h0 * 32 + cc + j];
        as1v[j] = a_src[(h0 + 2) * 32 + cc + j];
        ad0[j] = a_dst[h0 * 32 + cc + j];
        ad1v[j] = a_dst[(h0 + 2) * 32 + cc + j];
    }
#pragma unroll
    for (int r = 0; r < 8; ++r) {
        int row = row0 + r0 + r;
        float4 a0 = acc[r][0], a1 = acc[r][1];
        float ps0 = a0.x * as0[0] + a0.y * as0[1] + a0.z * as0[2] + a0.w * as0[3];
        float ps1 = a1.x * as1v[0] + a1.y * as1v[1] + a1.z * as1v[2] + a1.w * as1v[3];
        float pd0 = a0.x * ad0[0] + a0.y * ad0[1] + a0.z * ad0[2] + a0.w * ad0[3];
        float pd1 = a1.x * ad1v[0] + a1.y * ad1v[1] + a1.z * ad1v[2] + a1.w * ad1v[3];
#pragma unroll
        for (int o = 1; o < 8; o <<= 1) {
            ps0 += __shfl_xor(ps0, o); ps1 += __shfl_xor(ps1, o);
            pd0 += __shfl_xor(pd0, o); pd1 += __shfl_xor(pd1, o);
        }
        if (row < n) {
            H4 u0, u1;
            u0.h[0] = half2v{(_Float16)a0.x, (_Float16)a0.y};
            u0.h[1] = half2v{(_Float16)a0.z, (_Float16)a0.w};
            u1.h[0] = half2v{(_Float16)a1.x, (_Float16)a1.y};
            u1.h[1] = half2v{(_Float16)a1.z, (_Float16)a1.w};
            *(float2*)&h1h[(size_t)row * 128 + c0] = u0.f2;
            *(float2*)&h1h[(size_t)row * 128 + c0 + 64] = u1.f2;
            if ((tid & 7) == 0) {
                as1[row * 4 + h0] = ps0; as1[row * 4 + h0 + 2] = ps1;
                ad1[row * 4 + h0] = pd0; ad1[row * 4 + h0 + 2] = pd1;
            }
        }
    }
}

// ---------------- GEMM2: h2 = hp @ W2 (fp16 in/out) + fused alpha dots ----------------

__global__ __launch_bounds__(256) void gemm2_kernel(const _Float16* __restrict__ hph,
                                                    const float* __restrict__ W2,
                                                    const float* __restrict__ a_src,
                                                    const float* __restrict__ a_dst,
                                                    _Float16* __restrict__ h2h,
                                                    float* __restrict__ as2,
                                                    float* __restrict__ ad2, int n) {
    __shared__ float Wl[128 * 32];
    __shared__ float xl[32][129];
    int tid = threadIdx.x;
    const float4* W4 = (const float4*)W2;
    float4* Wl4 = (float4*)Wl;
#pragma unroll
    for (int i = 0; i < 4; ++i) Wl4[tid + i * 256] = W4[tid + i * 256];
    int row0 = blockIdx.x * 32;
    for (int f = tid; f < 32 * 128; f += 256) {
        int r = f >> 7, k = f & 127;
        int row = row0 + r;
        xl[r][k] = (row < n) ? (float)hph[(size_t)row * 128 + k] : 0.f;
    }
    __syncthreads();
    int cg = tid & 7, r = tid >> 3;
    int c0 = cg * 4;
    float a0 = 0, a1 = 0, a2 = 0, a3 = 0;
    for (int k = 0; k < 128; ++k) {
        float4 w = *(const float4*)&Wl[k * 32 + c0];
        float xv = xl[r][k];
        a0 += xv * w.x; a1 += xv * w.y; a2 += xv * w.z; a3 += xv * w.w;
    }
    float ps = a0 * a_src[c0] + a1 * a_src[c0 + 1] + a2 * a_src[c0 + 2] + a3 * a_src[c0 + 3];
    float pd = a0 * a_dst[c0] + a1 * a_dst[c0 + 1] + a2 * a_dst[c0 + 2] + a3 * a_dst[c0 + 3];
#pragma unroll
    for (int o = 1; o < 8; o <<= 1) { ps += __shfl_xor(ps, o); pd += __shfl_xor(pd, o); }
    int row = row0 + r;
    if (row < n) {
        H4 u;
        u.h[0] = half2v{(_Float16)a0, (_Float16)a1};
        u.h[1] = half2v{(_Float16)a2, (_Float16)a3};
        *(float2*)&h2h[(size_t)row * 32 + c0] = u.f2;
        if (cg == 0) { as2[row] = ps; ad2[row] = pd; }
    }
}

// ---------------- layer-1 softmax + aggregate: wave/node, fp16 gather ----------------

__global__ __launch_bounds__(256) void agg1_kernel(const _Float16* __restrict__ h1h,
                                                   const float4* __restrict__ as1,
                                                   const float4* __restrict__ ad1,
                                                   const int* __restrict__ rp,
                                                   const int* __restrict__ col,
                                                   const float* __restrict__ b1,
                                                   _Float16* __restrict__ hph, int n) {
    __shared__ float4 s_p[4][64];
    int wave = threadIdx.x >> 6, lane = threadIdx.x & 63;
    int nid = blockIdx.x * 4 + wave;
    if (nid >= n) return;
    int start = rp[nid], end = rp[nid + 1];
    float4 adn = ad1[nid], asn = as1[nid];
    float4 psf;
    psf.x = __expf(leaky(asn.x + adn.x));
    psf.y = __expf(leaky(asn.y + adn.y));
    psf.z = __expf(leaky(asn.z + adn.z));
    psf.w = __expf(leaky(asn.w + adn.w));
    float4 dsum = make_float4(0.f, 0.f, 0.f, 0.f);
    int g = lane & 7, sub = lane >> 3;
    float4 aL0 = make_float4(0.f, 0.f, 0.f, 0.f);
    float4 aL1 = aL0, aH0 = aL0, aH1 = aL0;

    for (int base = start; base < end; base += 64) {
        int i = base + lane;
        int sidx = 0;
        float4 p = make_float4(0.f, 0.f, 0.f, 0.f);
        if (i < end) {
            sidx = col[i];
            float4 a = as1[sidx];
            p.x = __expf(leaky(a.x + adn.x));
            p.y = __expf(leaky(a.y + adn.y));
            p.z = __expf(leaky(a.z + adn.z));
            p.w = __expf(leaky(a.w + adn.w));
            dsum.x += p.x; dsum.y += p.y; dsum.z += p.z; dsum.w += p.w;
        }
        s_p[wave][lane] = p;         // intra-wave LDS, program order per wave
        int len = min(64, end - base);
        int steps = (len + 7) >> 3;  // wave-uniform
        for (int s = 0; s < steps; ++s) {
            int j = s * 8 + sub;
            int js = (j < len) ? j : 0;
            int rj = __shfl(sidx, js);           // all 64 lanes active
            if (j < len) {
                float4 pv = s_p[wave][js];
                float wl = (g < 4) ? pv.x : pv.y;
                float wh = (g < 4) ? pv.z : pv.w;
                const H8* row = (const H8*)(h1h + (size_t)rj * 128);
                H8 u0 = row[g], u1 = row[8 + g];
                aL0.x += (float)u0.h[0].x * wl; aL0.y += (float)u0.h[0].y * wl;
                aL0.z += (float)u0.h[1].x * wl; aL0.w += (float)u0.h[1].y * wl;
                aL1.x += (float)u0.h[2].x * wl; aL1.y += (float)u0.h[2].y * wl;
                aL1.z += (float)u0.h[3].x * wl; aL1.w += (float)u0.h[3].y * wl;
                aH0.x += (float)u1.h[0].x * wh; aH0.y += (float)u1.h[0].y * wh;
                aH0.z += (float)u1.h[1].x * wh; aH0.w += (float)u1.h[1].y * wh;
                aH1.x += (float)u1.h[2].x * wh; aH1.y += (float)u1.h[2].y * wh;
                aH1.z += (float)u1.h[3].x * wh; aH1.w += (float)u1.h[3].y * wh;
            }
        }
    }
    // self loop (one edge-subset adds it)
    if (sub == 0) {
        float wl = (g < 4) ? psf.x : psf.y;
        float wh = (g < 4) ? psf.z : psf.w;
        const H8* row = (const H8*)(h1h + (size_t)nid * 128);
        H8 u0 = row[g], u1 = row[8 + g];
        aL0.x += (float)u0.h[0].x * wl; aL0.y += (float)u0.h[0].y * wl;
        aL0.z += (float)u0.h[1].x * wl; aL0.w += (float)u0.h[1].y * wl;
        aL1.x += (float)u0.h[2].x * wl; aL1.y += (float)u0.h[2].y * wl;
        aL1.z += (float)u0.h[3].x * wl; aL1.w += (float)u0.h[3].y * wl;
        aH0.x += (float)u1.h[0].x * wh; aH0.y += (float)u1.h[0].y * wh;
        aH0.z += (float)u1.h[1].x * wh; aH0.w += (float)u1.h[1].y * wh;
        aH1.x += (float)u1.h[2].x * wh; aH1.y += (float)u1.h[2].y * wh;
        aH1.z += (float)u1.h[3].x * wh; aH1.w += (float)u1.h[3].y * wh;
    }
    if (lane == 0) {
        dsum.x += psf.x; dsum.y += psf.y; dsum.z += psf.z; dsum.w += psf.w;
    }
#pragma unroll
    for (int o = 1; o < 64; o <<= 1) {
        dsum.x += __shfl_xor(dsum.x, o); dsum.y += __shfl_xor(dsum.y, o);
        dsum.z += __shfl_xor(dsum.z, o); dsum.w += __shfl_xor(dsum.w, o);
    }
#pragma unroll
    for (int o = 8; o < 64; o <<= 1) {    // reduce over edge subsets (same g)
        aL0.x += __shfl_xor(aL0.x, o); aL0.y += __shfl_xor(aL0.y, o);
        aL0.z += __shfl_xor(aL0.z, o); aL0.w += __shfl_xor(aL0.w, o);
        aL1.x += __shfl_xor(aL1.x, o); aL1.y += __shfl_xor(aL1.y, o);
        aL1.z += __shfl_xor(aL1.z, o); aL1.w += __shfl_xor(aL1.w, o);
        aH0.x += __shfl_xor(aH0.x, o); aH0.y += __shfl_xor(aH0.y, o);
        aH0.z += __shfl_xor(aH0.z, o); aH0.w += __shfl_xor(aH0.w, o);
        aH1.x += __shfl_xor(aH1.x, o); aH1.y += __shfl_xor(aH1.y, o);
        aH1.z += __shfl_xor(aH1.z, o); aH1.w += __shfl_xor(aH1.w, o);
    }
    if (sub == 0) {
        float i0 = __builtin_amdgcn_rcpf(dsum.x);
        float i1 = __builtin_amdgcn_rcpf(dsum.y);
        float i2 = __builtin_amdgcn_rcpf(dsum.z);
        float i3 = __builtin_amdgcn_rcpf(dsum.w);
        float il = (g < 4) ? i0 : i1;
        float ih = (g < 4) ? i2 : i3;
        const float4* b4 = (const float4*)b1;
        float4 bL0 = b4[g * 2], bL1 = b4[g * 2 + 1];
        float4 bH0 = b4[16 + g * 2], bH1 = b4[16 + g * 2 + 1];
        float4 r0 = make_float4(elu(aL0.x * il + bL0.x), elu(aL0.y * il + bL0.y),
                                elu(aL0.z * il + bL0.z), elu(aL0.w * il + bL0.w));
        float4 r1 = make_float4(elu(aL1.x * il + bL1.x), elu(aL1.y * il + bL1.y),
                                elu(aL1.z * il + bL1.z), elu(aL1.w * il + bL1.w));
        float4 r2 = make_float4(elu(aH0.x * ih + bH0.x), elu(aH0.y * ih + bH0.y),
                                elu(aH0.z * ih + bH0.z), elu(aH0.w * ih + bH0.w));
        float4 r3 = make_float4(elu(aH1.x * ih + bH1.x), elu(aH1.y * ih + bH1.y),
                                elu(aH1.z * ih + bH1.z), elu(aH1.w * ih + bH1.w));
        H8 oL, oH;
        oL.h[0] = half2v{(_Float16)r0.x, (_Float16)r0.y};
        oL.h[1] = half2v{(_Float16)r0.z, (_Float16)r0.w};
        oL.h[2] = half2v{(_Float16)r1.x, (_Float16)r1.y};
        oL.h[3] = half2v{(_Float16)r1.z, (_Float16)r1.w};
        oH.h[0] = half2v{(_Float16)r2.x, (_Float16)r2.y};
        oH.h[1] = half2v{(_Float16)r2.z, (_Float16)r2.w};
        oH.h[2] = half2v{(_Float16)r3.x, (_Float16)r3.y};
        oH.h[3] = half2v{(_Float16)r3.z, (_Float16)r3.w};
        *(float4*)&hph[(size_t)nid * 128 + g * 8] = oL.f4;
        *(float4*)&hph[(size_t)nid * 128 + 64 + g * 8] = oH.f4;
    }
}

// ---------------- layer-2 softmax + aggregate: wave/node, fp16 gather ----------------

__global__ __launch_bounds__(256) void agg2_kernel(const _Float16* __restrict__ h2h,
                                                   const float* __restrict__ as2,
                                                   const float* __restrict__ ad2,
                                                   const int* __restrict__ rp,
                                                   const int* __restrict__ col,
                                                   const float* __restrict__ b2,
                                                   float* __restrict__ out, int n) {
    int wave = threadIdx.x >> 6, lane = threadIdx.x & 63;
    int nid = blockIdx.x * 4 + wave;
    if (nid >= n) return;
    int start = rp[nid], end = rp[nid + 1];
    float adn = ad2[nid];
    float psf = __expf(leaky(as2[nid] + adn));
    float dsum = 0.f;
    int g = lane & 7, sub = lane >> 3;
    float4 acc = make_float4(0.f, 0.f, 0.f, 0.f);
    for (int base = start; base < end; base += 64) {
        int i = base + lane;
        int sidx = 0;
        float p = 0.f;
        if (i < end) {
            sidx = col[i];
            p = __expf(leaky(as2[sidx] + adn));
            dsum += p;
        }
        int len = min(64, end - base);
        int steps = (len + 7) >> 3;
        for (int s = 0; s < steps; ++s) {
            int j = s * 8 + sub;
            int js = (j < len) ? j : 0;
            int rj = __shfl(sidx, js);
            float pj = __shfl(p, js);
            if (j < len) {
                H4 u = ((const H4*)(h2h + (size_t)rj * 32))[g];
                acc.x += (float)u.h[0].x * pj; acc.y += (float)u.h[0].y * pj;
                acc.z += (float)u.h[1].x * pj; acc.w += (float)u.h[1].y * pj;
            }
        }
    }
    if (sub == 0) {
        H4 u = ((const H4*)(h2h + (size_t)nid * 32))[g];
        acc.x += (float)u.h[0].x * psf; acc.y += (float)u.h[0].y * psf;
        acc.z += (float)u.h[1].x * psf; acc.w += (float)u.h[1].y * psf;
    }
    if (lane == 0) dsum += psf;
#pragma unroll
    for (int o = 1; o < 64; o <<= 1) dsum += __shfl_xor(dsum, o);
#pragma unroll
    for (int o = 8; o < 64; o <<= 1) {
        acc.x += __shfl_xor(acc.x, o); acc.y += __shfl_xor(acc.y, o);
        acc.z += __shfl_xor(acc.z, o); acc.w += __shfl_xor(acc.w, o);
    }
    if (sub == 0) {
        float inv = __builtin_amdgcn_rcpf(dsum);
        float4 bb = ((const float4*)b2)[g];
        ((float4*)(out + (size_t)nid * 32))[g] =
            make_float4(acc.x * inv + bb.x, acc.y * inv + bb.y,
                        acc.z * inv + bb.z, acc.w * inv + bb.w);
    }
}

// ---------------- launch ----------------

extern "C" void kernel_launch(void* const* d_in, const int* in_sizes, int n_in,
                              void* d_out, int out_size, void* d_ws, size_t ws_size,
                              hipStream_t stream) {
    const float* x      = (const float*)d_in[0];
    const int*   ei     = (const int*)d_in[1];
    const float* W1     = (const float*)d_in[2];
    const float* a_src1 = (const float*)d_in[3];
    const float* a_dst1 = (const float*)d_in[4];
    const float* b1     = (const float*)d_in[5];
    const float* W2     = (const float*)d_in[6];
    const float* a_src2 = (const float*)d_in[7];
    const float* a_dst2 = (const float*)d_in[8];
    const float* b2     = (const float*)d_in[9];
    float* out = (float*)d_out;

    const int N = in_sizes[0] / 128;
    const int E = in_sizes[1] / 2;
    const int* src = ei;
    const int* dstp = ei + E;

    uint8_t* w = (uint8_t*)d_ws;
    auto carve = [&](size_t bytes) {
        uint8_t* p = w;
        w += (bytes + 255) & ~(size_t)255;
        return p;
    };
    _Float16* h1h = (_Float16*)carve((size_t)N * 128 * 2);
    _Float16* hph = (_Float16*)carve((size_t)N * 128 * 2);
    _Float16* h2h = (_Float16*)carve((size_t)N * 32 * 2);
    float* as1 = (float*)carve((size_t)N * 4 * 4);
    float* ad1 = (float*)carve((size_t)N * 4 * 4);
    float* as2 = (float*)carve((size_t)N * 4);
    float* ad2 = (float*)carve((size_t)N * 4);
    int* rp   = (int*)carve((size_t)(N + 1) * 4);
    int* cnt  = (int*)carve((size_t)N * 4);
    int* cur  = (int*)carve((size_t)N * 4);
    int* col  = (int*)carve((size_t)E * 4);
    int* bsum = (int*)carve(1024 * 4);

    const int G = (N + 1023) / 1024;   // <= 1024

    // CSR build (multi-dispatch)
    hipMemsetAsync(cnt, 0, (size_t)N * 4, stream);
    count_kernel<<<(E + 255) / 256, 256, 0, stream>>>(dstp, cnt, E);
    scanA_kernel<<<G, 256, 0, stream>>>(cnt, bsum, N);
    scanB_kernel<<<1, 1024, 0, stream>>>(bsum, G);
    scanC_kernel<<<G, 256, 0, stream>>>(cnt, bsum, rp, cur, N);
    scatter_kernel<<<(E + 255) / 256, 256, 0, stream>>>(src, dstp, cur, col, E);

    // layer 1
    gemm1_kernel<<<(N + 63) / 64, 128, 0, stream>>>(x, W1, a_src1, a_dst1, h1h, as1, ad1, N);
    agg1_kernel<<<(N + 3) / 4, 256, 0, stream>>>(h1h, (const float4*)as1, (const float4*)ad1,
                                                 rp, col, b1, hph, N);
    // layer 2
    gemm2_kernel<<<(N + 31) / 32, 256, 0, stream>>>(hph, W2, a_src2, a_dst2, h2h, as2, ad2, N);
    agg2_kernel<<<(N + 3) / 4, 256, 0, stream>>>(h2h, as2, ad2, rp, col, b2, out, N);
}